// Round 1
// 653.921 us; speedup vs baseline: 1.0081x; 1.0081x over previous
//
#include <hip/hip_runtime.h>
#include <math.h>

#define BB 1024
#define PP 64
#define NN 512
#define EE 256

// per-batch output layout (floats): [feas 64 | workers 128 | known 4096 |
// unknown 4096 | differ 4096 | qa 64 | agg 256] = 12800
// float4 units: 16 | 32 | 1024 | 1024 | 1024 | 16 | 64 = 3200

#define LDA 264  // bf16 elems per LDS A-row (256 + 8 pad)

typedef short bf16x8 __attribute__((ext_vector_type(8)));
typedef short bf16x4 __attribute__((ext_vector_type(4)));
typedef float f32x4  __attribute__((ext_vector_type(4)));

__device__ inline unsigned short f2bf(float x) {
    union { float f; unsigned int u; } v; v.f = x;
    unsigned int r = (v.u + 0x7FFFu + ((v.u >> 16) & 1u)) >> 16;
    return (unsigned short)r;
}

// fast tanh: tanh(x) = sign(x) * (1 - e) / (1 + e), e = exp(-2|x|)
// 1 v_exp + 1 v_rcp; |err| ~1e-6, well below bf16 GEMM noise.
__device__ inline float fast_tanh(float x) {
    float ax = fabsf(x);
    float e  = __expf(-2.0f * ax);
    float y  = (1.0f - e) * __builtin_amdgcn_rcpf(1.0f + e);
    return copysignf(y, x);
}

// Repack W (E x E fp32, row-major, W[k][f]) into MFMA B-fragment order (bf16):
// for f-tile t (16 cols), k-chunk c (32 k), lane l: n = 16t+(l&15), k = 32c+(l>>4)*8+j
// flat dst = ((t*8+c)*64 + l)*8 + j  -> one contiguous 16B load per lane per frag.
__global__ void wconv_kernel(const float* __restrict__ W,
                             unsigned short* __restrict__ Wt) {
    int i = blockIdx.x * blockDim.x + threadIdx.x;  // 0..65535
    int k = i >> 8;
    int f = i & 255;
    int t = f >> 4;
    int c = k >> 5;
    int kk = k & 31;
    int lane = (kk >> 3) * 16 + (f & 15);
    int dst = (((t * 8 + c) * 64) + lane) * 8 + (kk & 7);
    Wt[dst] = f2bf(W[i]);
}

// One block per batch: does the whole concat copy AND the gather+GEMM+tanh+avg.
// 1024 blocks * 256 thr, 33 KB LDS, <=128 VGPR -> 4 blocks/CU, fully resident.
__global__ __launch_bounds__(256, 4) void fused_kernel(
    const float* __restrict__ feas, const float* __restrict__ workers,
    const float* __restrict__ known, const float* __restrict__ unknown,
    const float* __restrict__ differ, const float* __restrict__ qa,
    const int* __restrict__ pn, const float* __restrict__ embed,
    const float* __restrict__ bias, const unsigned short* __restrict__ Wt,
    float* __restrict__ out)
{
    __shared__ unsigned short sA[PP * LDA];
    const int b = blockIdx.x;
    const int tid = threadIdx.x;
    const int wave = tid >> 6, lane = tid & 63;

    // ---- gather: wave-per-row. Each wave instruction reads one contiguous
    // 1 KB embed row (lane l -> float4 l). 16 rows per wave.
    {
        const int* pnb = pn + b * PP;
        const float* ebase = embed + (size_t)b * NN * EE;
        #pragma unroll
        for (int i = 0; i < 16; ++i) {
            const int p = wave * 16 + i;
            const float4 v =
                ((const float4*)(ebase + (size_t)pnb[p] * EE))[lane];
            bf16x4 t;
            t[0] = (short)f2bf(v.x);
            t[1] = (short)f2bf(v.y);
            t[2] = (short)f2bf(v.z);
            t[3] = (short)f2bf(v.w);
            *(bf16x4*)(sA + p * LDA + lane * 4) = t;  // ds_write_b64, 8B aligned
        }
    }

    float4* out4 = (float4*)out + (size_t)b * 3200;

    // ---- copy part 1 (independent traffic hides gather/LDS latency) ----
    if (tid < 64) {
        if (tid < 16)      out4[tid]        = ((const float4*)feas)[b * 16 + tid];
        else if (tid < 48) out4[tid]        = ((const float4*)workers)[b * 32 + tid - 16];
        else               out4[3072 + tid] = ((const float4*)qa)[b * 16 + tid - 48];
    }
    {
        const float4* s = (const float4*)known + (size_t)b * 1024;
        #pragma unroll
        for (int k = 0; k < 4; ++k)
            out4[48 + k * 256 + tid] = s[k * 256 + tid];
    }

    __syncthreads();

    // ---- MFMA: 64x256 @ 256x256, K=256 in 8 chunks of 32 ----
    const int m = lane & 15, quad = lane >> 4;
    f32x4 acc[4][4];  // [m-tile][f-tile]
    #pragma unroll
    for (int mt = 0; mt < 4; ++mt)
        #pragma unroll
        for (int ft = 0; ft < 4; ++ft)
            acc[mt][ft] = (f32x4){0.f, 0.f, 0.f, 0.f};

    #pragma unroll
    for (int c = 0; c < 8; ++c) {
        bf16x8 aF[4], bF[4];
        #pragma unroll
        for (int mt = 0; mt < 4; ++mt)
            aF[mt] = *(const bf16x8*)(sA + (mt * 16 + m) * LDA + c * 32 + quad * 8);
        #pragma unroll
        for (int ft = 0; ft < 4; ++ft)
            bF[ft] = *(const bf16x8*)(Wt + ((((wave * 4 + ft) * 8 + c) * 64) + lane) * 8);
        #pragma unroll
        for (int mt = 0; mt < 4; ++mt)
            #pragma unroll
            for (int ft = 0; ft < 4; ++ft)
                acc[mt][ft] = __builtin_amdgcn_mfma_f32_16x16x32_bf16(
                    aF[mt], bF[ft], acc[mt][ft], 0, 0, 0);
    }

    // ---- epilogue: tanh(C + bias), sum over 64 p-rows, /64 ----
    // C/D layout: col(f) = lane&15, row(p) = mt*16 + quad*4 + reg
    const float inv = 1.0f / 64.0f;
    #pragma unroll
    for (int ft = 0; ft < 4; ++ft) {
        const int f = wave * 64 + ft * 16 + m;
        const float bia = bias[f];
        float s = 0.f;
        #pragma unroll
        for (int mt = 0; mt < 4; ++mt)
            #pragma unroll
            for (int r = 0; r < 4; ++r)
                s += fast_tanh(acc[mt][ft][r] + bia);
        s += __shfl_xor(s, 16, 64);
        s += __shfl_xor(s, 32, 64);
        if (quad == 0)
            out[(size_t)b * 12800 + 12544 + f] = s * inv;
    }

    // ---- copy part 2 ----
    {
        const float4* su = (const float4*)unknown + (size_t)b * 1024;
        const float4* sd = (const float4*)differ + (size_t)b * 1024;
        #pragma unroll
        for (int k = 0; k < 4; ++k)
            out4[1072 + k * 256 + tid] = su[k * 256 + tid];
        #pragma unroll
        for (int k = 0; k < 4; ++k)
            out4[2096 + k * 256 + tid] = sd[k * 256 + tid];
    }
}

extern "C" void kernel_launch(void* const* d_in, const int* in_sizes, int n_in,
                              void* d_out, int out_size, void* d_ws, size_t ws_size,
                              hipStream_t stream) {
    const float* feas    = (const float*)d_in[0];
    const float* workers = (const float*)d_in[1];
    const float* known   = (const float*)d_in[2];
    const float* unknown = (const float*)d_in[3];
    const float* differ  = (const float*)d_in[4];
    const float* qa      = (const float*)d_in[5];
    const int*   pn      = (const int*)d_in[6];
    const float* embed   = (const float*)d_in[7];
    const float* W       = (const float*)d_in[8];
    const float* bias    = (const float*)d_in[9];
    float* out = (float*)d_out;
    unsigned short* Wt = (unsigned short*)d_ws;  // 128 KB of workspace

    wconv_kernel<<<256, 256, 0, stream>>>(W, Wt);
    fused_kernel<<<BB, 256, 0, stream>>>(feas, workers, known, unknown,
                                         differ, qa, pn, embed, bias, Wt,
                                         out);
}